// Round 2
// baseline (357.900 us; speedup 1.0000x reference)
//
#include <hip/hip_runtime.h>

// Trilinear interpolation over a 256^3 f32 grid.
// Round 2: spatially bucket points (16^3-cell bins -> 4096 bins) via counting
// sort, then interpolate in sorted order so gathers hit L1/L2.
// Pipeline: zero hist -> key+hist -> scan(4096) -> scatter sorted float4 ->
// interp sorted + scatter out[idx]. Fallback to direct kernel if ws too small.

#define NX 256
#define NY 256
#define NZ 256
#define NBINS 4096   // 16 x 16 x 16 bins of 16^3 cells each

__device__ __forceinline__ float interp_one(float ix, float iy, float iz,
                                            const float* __restrict__ g,
                                            bool& valid) {
    valid = (ix >= 0.0f) && (ix <= (float)(NX - 1)) &&
            (iy >= 0.0f) && (iy <= (float)(NY - 1)) &&
            (iz >= 0.0f) && (iz <= (float)(NZ - 1));
    if (!valid) return 0.0f;

    float flx = floorf(ix), fcx = ceilf(ix);
    float fly = floorf(iy), fcy = ceilf(iy);
    float flz = floorf(iz), fcz = ceilf(iz);

    int x0 = (int)flx, x1 = (int)fcx;
    int y0 = (int)fly, y1 = (int)fcy;
    int z0 = (int)flz, z1 = (int)fcz;

    float wsx = ix - flx; if (wsx == 0.0f) wsx = 1.0f;
    float wux = fcx - ix; if (wux == 0.0f) wux = 1.0f;
    float wsy = iy - fly; if (wsy == 0.0f) wsy = 1.0f;
    float wuy = fcy - iy; if (wuy == 0.0f) wuy = 1.0f;
    float wsz = iz - flz; if (wsz == 0.0f) wsz = 1.0f;
    float wuz = fcz - iz; if (wuz == 0.0f) wuz = 1.0f;

    int bx0 = x0 << 16, bx1 = x1 << 16;
    int by0 = y0 << 8,  by1 = y1 << 8;

    float v0 = g[bx0 + by0 + z0];  float w0 = wux * wuy * wuz;
    float v1 = g[bx1 + by0 + z0];  float w1 = wsx * wuy * wuz;
    float v2 = g[bx0 + by1 + z0];  float w2 = wux * wsy * wuz;
    float v3 = g[bx1 + by1 + z0];  float w3 = wsx * wsy * wuz;
    float v4 = g[bx0 + by0 + z1];  float w4 = wux * wuy * wsz;
    float v5 = g[bx1 + by0 + z1];  float w5 = wsx * wuy * wsz;
    float v6 = g[bx0 + by1 + z1];  float w6 = wux * wsy * wsz;
    float v7 = g[bx1 + by1 + z1];  float w7 = wsx * wsy * wsz;

    float num = v0 * w0 + v1 * w1 + v2 * w2 + v3 * w3 +
                v4 * w4 + v5 * w5 + v6 * w6 + v7 * w7;
    float den = w0 + w1 + w2 + w3 + w4 + w5 + w6 + w7;
    return num / den;
}

// ---------- fallback (round-1) kernel ----------
__global__ __launch_bounds__(256) void simplegrid_direct(
    const float* __restrict__ x, const float* __restrict__ grid,
    const float* __restrict__ lower, const float* __restrict__ res,
    float* __restrict__ out, int n)
{
    int i = blockIdx.x * blockDim.x + threadIdx.x;
    if (i >= n) return;
    float ix = (x[3 * i + 0] - lower[0]) / res[0];
    float iy = (x[3 * i + 1] - lower[1]) / res[1];
    float iz = (x[3 * i + 2] - lower[2]) / res[2];
    bool valid;
    float v = interp_one(ix, iy, iz, grid, valid);
    out[i] = valid ? v : 0.0f;
}

// ---------- sorted pipeline ----------
__global__ __launch_bounds__(256) void zero_hist_kernel(unsigned* hist) {
    int i = blockIdx.x * blockDim.x + threadIdx.x;
    if (i < NBINS) hist[i] = 0u;
}

__global__ __launch_bounds__(256) void key_hist_kernel(
    const float* __restrict__ x, const float* __restrict__ lower,
    const float* __restrict__ res, unsigned short* __restrict__ keys,
    unsigned* __restrict__ hist, int n)
{
    int i = blockIdx.x * blockDim.x + threadIdx.x;
    if (i >= n) return;
    float ix = (x[3 * i + 0] - lower[0]) / res[0];
    float iy = (x[3 * i + 1] - lower[1]) / res[1];
    float iz = (x[3 * i + 2] - lower[2]) / res[2];
    ix = fminf(fmaxf(ix, 0.0f), 255.0f);
    iy = fminf(fmaxf(iy, 0.0f), 255.0f);
    iz = fminf(fmaxf(iz, 0.0f), 255.0f);
    int bx = ((int)ix) >> 4;
    int by = ((int)iy) >> 4;
    int bz = ((int)iz) >> 4;
    unsigned key = (unsigned)((bx << 8) | (by << 4) | bz);
    keys[i] = (unsigned short)key;
    atomicAdd(&hist[key], 1u);
}

__global__ __launch_bounds__(1024) void scan_kernel(
    const unsigned* __restrict__ hist, unsigned* __restrict__ cursor)
{
    __shared__ unsigned tsum[1024];
    int t = threadIdx.x;                 // 1024 threads, 4 bins each
    unsigned h0 = hist[4 * t + 0];
    unsigned h1 = hist[4 * t + 1];
    unsigned h2 = hist[4 * t + 2];
    unsigned h3 = hist[4 * t + 3];
    unsigned s = h0 + h1 + h2 + h3;
    tsum[t] = s;
    __syncthreads();
    for (int off = 1; off < 1024; off <<= 1) {
        unsigned v = (t >= off) ? tsum[t - off] : 0u;
        __syncthreads();
        tsum[t] += v;
        __syncthreads();
    }
    unsigned excl = tsum[t] - s;         // exclusive prefix of this thread's 4
    cursor[4 * t + 0] = excl;
    cursor[4 * t + 1] = excl + h0;
    cursor[4 * t + 2] = excl + h0 + h1;
    cursor[4 * t + 3] = excl + h0 + h1 + h2;
}

__global__ __launch_bounds__(256) void scatter_kernel(
    const float* __restrict__ x, const unsigned short* __restrict__ keys,
    unsigned* __restrict__ cursor, float4* __restrict__ sorted, int n)
{
    int i = blockIdx.x * blockDim.x + threadIdx.x;
    if (i >= n) return;
    unsigned key = keys[i];
    unsigned pos = atomicAdd(&cursor[key], 1u);
    float4 p;
    p.x = x[3 * i + 0];
    p.y = x[3 * i + 1];
    p.z = x[3 * i + 2];
    p.w = __int_as_float(i);
    sorted[pos] = p;
}

__global__ __launch_bounds__(256) void interp_sorted_kernel(
    const float4* __restrict__ sorted, const float* __restrict__ grid,
    const float* __restrict__ lower, const float* __restrict__ res,
    float* __restrict__ out, int n)
{
    int j = blockIdx.x * blockDim.x + threadIdx.x;
    if (j >= n) return;
    float4 p = sorted[j];
    float ix = (p.x - lower[0]) / res[0];
    float iy = (p.y - lower[1]) / res[1];
    float iz = (p.z - lower[2]) / res[2];
    bool valid;
    float v = interp_one(ix, iy, iz, grid, valid);
    int idx = __float_as_int(p.w);
    out[idx] = valid ? v : 0.0f;
}

extern "C" void kernel_launch(void* const* d_in, const int* in_sizes, int n_in,
                              void* d_out, int out_size, void* d_ws, size_t ws_size,
                              hipStream_t stream) {
    const float* x     = (const float*)d_in[0];
    const float* grid  = (const float*)d_in[1];
    const float* lower = (const float*)d_in[2];
    const float* res   = (const float*)d_in[3];
    float* out = (float*)d_out;

    int n = in_sizes[0] / 3;
    int block = 256;
    int blocks = (n + block - 1) / block;

    // workspace layout (256B-aligned chunks)
    size_t off_hist   = 0;
    size_t off_cursor = off_hist + NBINS * sizeof(unsigned);          // 16 KB
    size_t off_keys   = off_cursor + NBINS * sizeof(unsigned);        // 16 KB
    size_t keys_bytes = ((size_t)n * sizeof(unsigned short) + 255) & ~(size_t)255;
    size_t off_sorted = off_keys + keys_bytes;
    size_t needed     = off_sorted + (size_t)n * sizeof(float4);

    if (ws_size < needed) {
        simplegrid_direct<<<blocks, block, 0, stream>>>(x, grid, lower, res, out, n);
        return;
    }

    char* ws = (char*)d_ws;
    unsigned*       hist   = (unsigned*)(ws + off_hist);
    unsigned*       cursor = (unsigned*)(ws + off_cursor);
    unsigned short* keys   = (unsigned short*)(ws + off_keys);
    float4*         sorted = (float4*)(ws + off_sorted);

    zero_hist_kernel<<<(NBINS + 255) / 256, 256, 0, stream>>>(hist);
    key_hist_kernel<<<blocks, block, 0, stream>>>(x, lower, res, keys, hist, n);
    scan_kernel<<<1, 1024, 0, stream>>>(hist, cursor);
    scatter_kernel<<<blocks, block, 0, stream>>>(x, keys, cursor, sorted, n);
    interp_sorted_kernel<<<blocks, block, 0, stream>>>(sorted, grid, lower, res, out, n);
}

// Round 3
// 166.122 us; speedup vs baseline: 2.1544x; 2.1544x over previous
//
#include <hip/hip_runtime.h>

// Trilinear interpolation over a 256^3 f32 grid. Round 3:
//  - 64 coarse spatial bins (64^3 cells each, ~1.07 MB grid footprint)
//  - block-aggregated counting sort: LDS reorder of 2048 pts/block, <=64
//    global atomics per block, contiguous segment flush (near-full-line writes)
//  - interp kernel pins each bin to one XCD (blockIdx&7) so the grid is
//    fetched ~once chip-wide into L2
//  - output goes out_sorted (streaming) + pos, then a gather-permute pass
//    (avoids random 4B scatter write-allocate)

#define NXG 256
#define CELL_SHIFT 6          // 64 cells per bin axis
#define NBA 4                 // bins per axis
#define NBINS 64
#define PTS_PER_BLK 2048
#define PPT 8                 // points per thread (hist/scatter), block=256

__device__ __forceinline__ float interp_one(float ix, float iy, float iz,
                                            const float* __restrict__ g,
                                            bool& valid) {
    valid = (ix >= 0.0f) && (ix <= 255.0f) &&
            (iy >= 0.0f) && (iy <= 255.0f) &&
            (iz >= 0.0f) && (iz <= 255.0f);
    if (!valid) return 0.0f;

    float flx = floorf(ix), fcx = ceilf(ix);
    float fly = floorf(iy), fcy = ceilf(iy);
    float flz = floorf(iz), fcz = ceilf(iz);

    int x0 = (int)flx, x1 = (int)fcx;
    int y0 = (int)fly, y1 = (int)fcy;
    int z0 = (int)flz, z1 = (int)fcz;

    float wsx = ix - flx; if (wsx == 0.0f) wsx = 1.0f;
    float wux = fcx - ix; if (wux == 0.0f) wux = 1.0f;
    float wsy = iy - fly; if (wsy == 0.0f) wsy = 1.0f;
    float wuy = fcy - iy; if (wuy == 0.0f) wuy = 1.0f;
    float wsz = iz - flz; if (wsz == 0.0f) wsz = 1.0f;
    float wuz = fcz - iz; if (wuz == 0.0f) wuz = 1.0f;

    int bx0 = x0 << 16, bx1 = x1 << 16;
    int by0 = y0 << 8,  by1 = y1 << 8;

    float v0 = g[bx0 + by0 + z0];  float w0 = wux * wuy * wuz;
    float v1 = g[bx1 + by0 + z0];  float w1 = wsx * wuy * wuz;
    float v2 = g[bx0 + by1 + z0];  float w2 = wux * wsy * wuz;
    float v3 = g[bx1 + by1 + z0];  float w3 = wsx * wsy * wuz;
    float v4 = g[bx0 + by0 + z1];  float w4 = wux * wuy * wsz;
    float v5 = g[bx1 + by0 + z1];  float w5 = wsx * wuy * wsz;
    float v6 = g[bx0 + by1 + z1];  float w6 = wux * wsy * wsz;
    float v7 = g[bx1 + by1 + z1];  float w7 = wsx * wsy * wsz;

    float num = v0 * w0 + v1 * w1 + v2 * w2 + v3 * w3 +
                v4 * w4 + v5 * w5 + v6 * w6 + v7 * w7;
    float den = w0 + w1 + w2 + w3 + w4 + w5 + w6 + w7;
    return num / den;
}

__device__ __forceinline__ unsigned bin_key(float ix, float iy, float iz) {
    ix = fminf(fmaxf(ix, 0.0f), 255.0f);
    iy = fminf(fmaxf(iy, 0.0f), 255.0f);
    iz = fminf(fmaxf(iz, 0.0f), 255.0f);
    int bx = ((int)ix) >> CELL_SHIFT;
    int by = ((int)iy) >> CELL_SHIFT;
    int bz = ((int)iz) >> CELL_SHIFT;
    return (unsigned)((bx << 4) | (by << 2) | bz);   // 64 bins
}

// ---------- fallback (round-1) kernel ----------
__global__ __launch_bounds__(256) void simplegrid_direct(
    const float* __restrict__ x, const float* __restrict__ grid,
    const float* __restrict__ lower, const float* __restrict__ res,
    float* __restrict__ out, int n)
{
    int i = blockIdx.x * blockDim.x + threadIdx.x;
    if (i >= n) return;
    float ix = (x[3 * i + 0] - lower[0]) / res[0];
    float iy = (x[3 * i + 1] - lower[1]) / res[1];
    float iz = (x[3 * i + 2] - lower[2]) / res[2];
    bool valid;
    float v = interp_one(ix, iy, iz, grid, valid);
    out[i] = valid ? v : 0.0f;
}

// ---------- sorted pipeline ----------
__global__ __launch_bounds__(64) void zero_hist_kernel(unsigned* hist) {
    hist[threadIdx.x] = 0u;
}

__global__ __launch_bounds__(256) void hist_kernel(
    const float* __restrict__ x, const float* __restrict__ lower,
    const float* __restrict__ res, unsigned* __restrict__ hist, int n)
{
    __shared__ unsigned lcnt[NBINS];
    int t = threadIdx.x;
    if (t < NBINS) lcnt[t] = 0u;
    __syncthreads();

    float l0 = lower[0], l1 = lower[1], l2 = lower[2];
    float r0 = res[0],   r1 = res[1],   r2 = res[2];
    int base = blockIdx.x * PTS_PER_BLK;
    #pragma unroll
    for (int k = 0; k < PPT; ++k) {
        int p = base + k * 256 + t;
        if (p < n) {
            float ix = (x[3 * p + 0] - l0) / r0;
            float iy = (x[3 * p + 1] - l1) / r1;
            float iz = (x[3 * p + 2] - l2) / r2;
            atomicAdd(&lcnt[bin_key(ix, iy, iz)], 1u);
        }
    }
    __syncthreads();
    if (t < NBINS && lcnt[t]) atomicAdd(&hist[t], lcnt[t]);
}

__global__ __launch_bounds__(64) void scan64_kernel(
    const unsigned* __restrict__ hist, unsigned* __restrict__ cursor)
{
    int t = threadIdx.x;             // exactly one wave of 64
    unsigned v = hist[t];
    unsigned s = v;
    #pragma unroll
    for (int off = 1; off < 64; off <<= 1) {
        unsigned u = __shfl_up(s, off);
        if (t >= off) s += u;
    }
    cursor[t] = s - v;               // exclusive prefix
}

// write_pos=true : write pos[orig]=dst (for permute variant)
// write_pos=false: write orig[dst]=orig (interp scatters out directly)
__global__ __launch_bounds__(256) void scatter_kernel(
    const float* __restrict__ x, const float* __restrict__ lower,
    const float* __restrict__ res, unsigned* __restrict__ cursor,
    float* __restrict__ sx, float* __restrict__ sy, float* __restrict__ sz,
    unsigned* __restrict__ posbuf, int write_pos, int n)
{
    __shared__ float4  pay[PTS_PER_BLK];        // 32 KB
    __shared__ unsigned cnt[NBINS];
    __shared__ unsigned pfx[NBINS + 1];
    __shared__ unsigned lcur[NBINS];
    __shared__ unsigned gbase[NBINS];

    int t = threadIdx.x;
    if (t < NBINS) cnt[t] = 0u;
    __syncthreads();

    float l0 = lower[0], l1 = lower[1], l2 = lower[2];
    float r0 = res[0],   r1 = res[1],   r2 = res[2];
    int base = blockIdx.x * PTS_PER_BLK;

    float px[PPT], py[PPT], pz[PPT];
    unsigned key[PPT];
    #pragma unroll
    for (int k = 0; k < PPT; ++k) {
        int p = base + k * 256 + t;
        if (p < n) {
            px[k] = (x[3 * p + 0] - l0) / r0;
            py[k] = (x[3 * p + 1] - l1) / r1;
            pz[k] = (x[3 * p + 2] - l2) / r2;
            key[k] = bin_key(px[k], py[k], pz[k]);
            atomicAdd(&cnt[key[k]], 1u);
        }
    }
    __syncthreads();

    // prefix over 64 bins (first wave)
    if (t < NBINS) {
        unsigned v = cnt[t];
        unsigned s = v;
        #pragma unroll
        for (int off = 1; off < 64; off <<= 1) {
            unsigned u = __shfl_up(s, off);
            if (t >= off) s += u;
        }
        pfx[t] = s - v;
        lcur[t] = s - v;
        if (t == NBINS - 1) pfx[NBINS] = s;
    }
    __syncthreads();

    // place into LDS, bin-sorted
    #pragma unroll
    for (int k = 0; k < PPT; ++k) {
        int p = base + k * 256 + t;
        if (p < n) {
            unsigned lp = atomicAdd(&lcur[key[k]], 1u);
            pay[lp] = make_float4(px[k], py[k], pz[k], __int_as_float(p));
        }
    }
    // reserve global ranges (one atomic per non-empty bin)
    if (t < NBINS && cnt[t]) gbase[t] = atomicAdd(&cursor[t], cnt[t]);
    __syncthreads();

    unsigned total = pfx[NBINS];
    for (unsigned s = t; s < total; s += 256) {
        // binary search: bin b with pfx[b] <= s < pfx[b+1]
        unsigned lo = 0, hi = NBINS;
        #pragma unroll
        for (int it = 0; it < 6; ++it) {
            unsigned mid = (lo + hi) >> 1;
            if (pfx[mid] <= s) lo = mid; else hi = mid;
        }
        float4 p = pay[s];
        unsigned dst = gbase[lo] + (s - pfx[lo]);
        sx[dst] = p.x;
        sy[dst] = p.y;
        sz[dst] = p.z;
        unsigned orig = (unsigned)__float_as_int(p.w);
        if (write_pos) posbuf[orig] = dst;   // pos[orig] = sorted position
        else           posbuf[dst]  = orig;  // orig index at sorted position
    }
}

// Each bin is processed only by blocks whose (blockIdx&7) == (bin&7):
// pins each bin's ~1MB grid footprint to one XCD's L2.
__global__ __launch_bounds__(256) void interp_sorted_kernel(
    const float* __restrict__ sx, const float* __restrict__ sy,
    const float* __restrict__ sz, const float* __restrict__ grid,
    const unsigned* __restrict__ cursor,      // post-scatter: inclusive prefix
    const unsigned* __restrict__ origbuf,     // used if !use_outsorted
    float* __restrict__ outv,                 // out_sorted or out
    int use_outsorted)
{
    int xcd  = blockIdx.x & 7;
    int slot = blockIdx.x >> 3;               // 0..255
    int t = threadIdx.x;

    for (int b = xcd; b < NBINS; b += 8) {
        unsigned start = b ? cursor[b - 1] : 0u;
        unsigned end   = cursor[b];
        for (unsigned chunk = start + (unsigned)slot * 256; chunk < end; chunk += 256u * 256u) {
            unsigned j = chunk + t;
            if (j < end) {
                float ix = sx[j], iy = sy[j], iz = sz[j];
                bool valid;
                float v = interp_one(ix, iy, iz, grid, valid);
                v = valid ? v : 0.0f;
                if (use_outsorted) outv[j] = v;
                else               outv[origbuf[j]] = v;
            }
        }
    }
}

__global__ __launch_bounds__(256) void permute_kernel(
    const float* __restrict__ out_sorted, const unsigned* __restrict__ pos,
    float* __restrict__ out, int n)
{
    int i = blockIdx.x * blockDim.x + threadIdx.x;
    if (i < n) out[i] = out_sorted[pos[i]];
}

extern "C" void kernel_launch(void* const* d_in, const int* in_sizes, int n_in,
                              void* d_out, int out_size, void* d_ws, size_t ws_size,
                              hipStream_t stream) {
    const float* x     = (const float*)d_in[0];
    const float* grid  = (const float*)d_in[1];
    const float* lower = (const float*)d_in[2];
    const float* res   = (const float*)d_in[3];
    float* out = (float*)d_out;

    int n = in_sizes[0] / 3;
    int blocks_pt = (n + 255) / 256;

    // workspace layout
    size_t off_hist   = 0;                               // 64 u32
    size_t off_cursor = 256;                             // 64 u32
    size_t off_sx     = 512;
    size_t plane      = (((size_t)n * 4) + 255) & ~(size_t)255;
    size_t off_sy     = off_sx + plane;
    size_t off_sz     = off_sy + plane;
    size_t off_pos    = off_sz + plane;                  // pos or orig
    size_t off_osort  = off_pos + plane;
    size_t need_full  = off_osort + plane;               // ~40.5 MB
    size_t need_min   = off_osort;                       // ~32.5 MB

    if (ws_size < need_min) {
        simplegrid_direct<<<blocks_pt, 256, 0, stream>>>(x, grid, lower, res, out, n);
        return;
    }
    int use_permute = (ws_size >= need_full) ? 1 : 0;

    char* ws = (char*)d_ws;
    unsigned* hist   = (unsigned*)(ws + off_hist);
    unsigned* cursor = (unsigned*)(ws + off_cursor);
    float*    sx     = (float*)(ws + off_sx);
    float*    sy     = (float*)(ws + off_sy);
    float*    sz     = (float*)(ws + off_sz);
    unsigned* posbuf = (unsigned*)(ws + off_pos);
    float*    osort  = (float*)(ws + off_osort);

    int blocks_sort = (n + PTS_PER_BLK - 1) / PTS_PER_BLK;

    zero_hist_kernel<<<1, 64, 0, stream>>>(hist);
    hist_kernel<<<blocks_sort, 256, 0, stream>>>(x, lower, res, hist, n);
    scan64_kernel<<<1, 64, 0, stream>>>(hist, cursor);
    scatter_kernel<<<blocks_sort, 256, 0, stream>>>(
        x, lower, res, cursor, sx, sy, sz, posbuf, use_permute, n);

    if (use_permute) {
        interp_sorted_kernel<<<2048, 256, 0, stream>>>(
            sx, sy, sz, grid, cursor, nullptr, osort, 1);
        permute_kernel<<<blocks_pt, 256, 0, stream>>>(osort, posbuf, out, n);
    } else {
        interp_sorted_kernel<<<2048, 256, 0, stream>>>(
            sx, sy, sz, grid, cursor, posbuf, out, 0);
    }
}

// Round 4
// 156.812 us; speedup vs baseline: 2.2824x; 1.0594x over previous
//
#include <hip/hip_runtime.h>

// Trilinear interpolation over a 256^3 f32 grid. Round 4:
//  - 64 coarse spatial bins (64^3 cells, ~1.07 MB grid footprint each)
//  - block-aggregated counting sort (LDS reorder, <=64 atomics/block)
//  - scan uses permuted bin order rank(b)=((b&7)<<3)|(b>>3) so each XCD lane
//    (bins with b&7==x) is CONTIGUOUS in the sorted array
//  - interp: xcd=bid&7 pins each lane to one XCD; 192 slots/lane sweep the
//    lane front-to-back in 512-pt chunks -> ~3 bins (~3.2MB) live per L2
//  - streaming out_sorted + final gather-permute (no random 4B scatter)

#define CELL_SHIFT 6          // 64 cells per bin axis
#define NBINS 64
#define PTS_PER_BLK 2048
#define PPT 8                 // points per thread in hist/scatter (block=256)

#define ISLOTS 192            // interp slots per lane
#define IPPT 2                // interp points per thread
#define ICH (IPPT * 256)      // interp chunk size (points)

__device__ __forceinline__ float interp_one(float ix, float iy, float iz,
                                            const float* __restrict__ g,
                                            bool& valid) {
    valid = (ix >= 0.0f) && (ix <= 255.0f) &&
            (iy >= 0.0f) && (iy <= 255.0f) &&
            (iz >= 0.0f) && (iz <= 255.0f);
    if (!valid) return 0.0f;

    float flx = floorf(ix), fcx = ceilf(ix);
    float fly = floorf(iy), fcy = ceilf(iy);
    float flz = floorf(iz), fcz = ceilf(iz);

    int x0 = (int)flx, x1 = (int)fcx;
    int y0 = (int)fly, y1 = (int)fcy;
    int z0 = (int)flz, z1 = (int)fcz;

    float wsx = ix - flx; if (wsx == 0.0f) wsx = 1.0f;
    float wux = fcx - ix; if (wux == 0.0f) wux = 1.0f;
    float wsy = iy - fly; if (wsy == 0.0f) wsy = 1.0f;
    float wuy = fcy - iy; if (wuy == 0.0f) wuy = 1.0f;
    float wsz = iz - flz; if (wsz == 0.0f) wsz = 1.0f;
    float wuz = fcz - iz; if (wuz == 0.0f) wuz = 1.0f;

    int bx0 = x0 << 16, bx1 = x1 << 16;
    int by0 = y0 << 8,  by1 = y1 << 8;

    float v0 = g[bx0 + by0 + z0];  float w0 = wux * wuy * wuz;
    float v1 = g[bx1 + by0 + z0];  float w1 = wsx * wuy * wuz;
    float v2 = g[bx0 + by1 + z0];  float w2 = wux * wsy * wuz;
    float v3 = g[bx1 + by1 + z0];  float w3 = wsx * wsy * wuz;
    float v4 = g[bx0 + by0 + z1];  float w4 = wux * wuy * wsz;
    float v5 = g[bx1 + by0 + z1];  float w5 = wsx * wuy * wsz;
    float v6 = g[bx0 + by1 + z1];  float w6 = wux * wsy * wsz;
    float v7 = g[bx1 + by1 + z1];  float w7 = wsx * wsy * wsz;

    float num = v0 * w0 + v1 * w1 + v2 * w2 + v3 * w3 +
                v4 * w4 + v5 * w5 + v6 * w6 + v7 * w7;
    float den = w0 + w1 + w2 + w3 + w4 + w5 + w6 + w7;
    return num / den;
}

__device__ __forceinline__ unsigned bin_key(float ix, float iy, float iz) {
    ix = fminf(fmaxf(ix, 0.0f), 255.0f);
    iy = fminf(fmaxf(iy, 0.0f), 255.0f);
    iz = fminf(fmaxf(iz, 0.0f), 255.0f);
    int bx = ((int)ix) >> CELL_SHIFT;
    int by = ((int)iy) >> CELL_SHIFT;
    int bz = ((int)iz) >> CELL_SHIFT;
    return (unsigned)((bx << 4) | (by << 2) | bz);   // 64 bins
}

// ---------- fallback (round-1) kernel ----------
__global__ __launch_bounds__(256) void simplegrid_direct(
    const float* __restrict__ x, const float* __restrict__ grid,
    const float* __restrict__ lower, const float* __restrict__ res,
    float* __restrict__ out, int n)
{
    int i = blockIdx.x * blockDim.x + threadIdx.x;
    if (i >= n) return;
    float ix = (x[3 * i + 0] - lower[0]) / res[0];
    float iy = (x[3 * i + 1] - lower[1]) / res[1];
    float iz = (x[3 * i + 2] - lower[2]) / res[2];
    bool valid;
    float v = interp_one(ix, iy, iz, grid, valid);
    out[i] = valid ? v : 0.0f;
}

// ---------- sorted pipeline ----------
__global__ __launch_bounds__(64) void zero_hist_kernel(unsigned* hist) {
    hist[threadIdx.x] = 0u;
}

__global__ __launch_bounds__(256) void hist_kernel(
    const float* __restrict__ x, const float* __restrict__ lower,
    const float* __restrict__ res, unsigned* __restrict__ hist, int n)
{
    __shared__ unsigned lcnt[NBINS];
    int t = threadIdx.x;
    if (t < NBINS) lcnt[t] = 0u;
    __syncthreads();

    float l0 = lower[0], l1 = lower[1], l2 = lower[2];
    float r0 = res[0],   r1 = res[1],   r2 = res[2];
    int base = blockIdx.x * PTS_PER_BLK;
    #pragma unroll
    for (int k = 0; k < PPT; ++k) {
        int p = base + k * 256 + t;
        if (p < n) {
            float ix = (x[3 * p + 0] - l0) / r0;
            float iy = (x[3 * p + 1] - l1) / r1;
            float iz = (x[3 * p + 2] - l2) / r2;
            atomicAdd(&lcnt[bin_key(ix, iy, iz)], 1u);
        }
    }
    __syncthreads();
    if (t < NBINS && lcnt[t]) atomicAdd(&hist[t], lcnt[t]);
}

// Scan in permuted rank order rank(b) = ((b&7)<<3)|(b>>3) (involution), so
// bins with b&7==x (lane x, pinned to XCD x) occupy a contiguous range.
// Also writes lane_off[0..8] (lane starts, lane_off[8]=n).
__global__ __launch_bounds__(64) void scan64_kernel(
    const unsigned* __restrict__ hist, unsigned* __restrict__ cursor,
    unsigned* __restrict__ lane_off)
{
    int t = threadIdx.x;                       // t = rank
    int b = ((t & 7) << 3) | (t >> 3);         // bin at this rank
    unsigned v = hist[b];
    unsigned s = v;
    #pragma unroll
    for (int off = 1; off < 64; off <<= 1) {
        unsigned u = __shfl_up(s, off);
        if (t >= off) s += u;
    }
    cursor[b] = s - v;                         // exclusive prefix (permuted order)
    if ((t & 7) == 0) lane_off[t >> 3] = s - v;
    if (t == 63)      lane_off[8] = s;
}

__global__ __launch_bounds__(256) void scatter_kernel(
    const float* __restrict__ x, const float* __restrict__ lower,
    const float* __restrict__ res, unsigned* __restrict__ cursor,
    float* __restrict__ sx, float* __restrict__ sy, float* __restrict__ sz,
    unsigned* __restrict__ posbuf, int n)
{
    __shared__ float4  pay[PTS_PER_BLK];        // 32 KB
    __shared__ unsigned cnt[NBINS];
    __shared__ unsigned pfx[NBINS + 1];
    __shared__ unsigned lcur[NBINS];
    __shared__ unsigned gbase[NBINS];

    int t = threadIdx.x;
    if (t < NBINS) cnt[t] = 0u;
    __syncthreads();

    float l0 = lower[0], l1 = lower[1], l2 = lower[2];
    float r0 = res[0],   r1 = res[1],   r2 = res[2];
    int base = blockIdx.x * PTS_PER_BLK;

    float px[PPT], py[PPT], pz[PPT];
    unsigned key[PPT];
    #pragma unroll
    for (int k = 0; k < PPT; ++k) {
        int p = base + k * 256 + t;
        if (p < n) {
            px[k] = (x[3 * p + 0] - l0) / r0;
            py[k] = (x[3 * p + 1] - l1) / r1;
            pz[k] = (x[3 * p + 2] - l2) / r2;
            key[k] = bin_key(px[k], py[k], pz[k]);
            atomicAdd(&cnt[key[k]], 1u);
        }
    }
    __syncthreads();

    if (t < NBINS) {
        unsigned v = cnt[t];
        unsigned s = v;
        #pragma unroll
        for (int off = 1; off < 64; off <<= 1) {
            unsigned u = __shfl_up(s, off);
            if (t >= off) s += u;
        }
        pfx[t] = s - v;
        lcur[t] = s - v;
        if (t == NBINS - 1) pfx[NBINS] = s;
    }
    __syncthreads();

    #pragma unroll
    for (int k = 0; k < PPT; ++k) {
        int p = base + k * 256 + t;
        if (p < n) {
            unsigned lp = atomicAdd(&lcur[key[k]], 1u);
            pay[lp] = make_float4(px[k], py[k], pz[k], __int_as_float(p));
        }
    }
    if (t < NBINS && cnt[t]) gbase[t] = atomicAdd(&cursor[t], cnt[t]);
    __syncthreads();

    unsigned total = pfx[NBINS];
    for (unsigned s = t; s < total; s += 256) {
        unsigned lo = 0, hi = NBINS;
        #pragma unroll
        for (int it = 0; it < 6; ++it) {
            unsigned mid = (lo + hi) >> 1;
            if (pfx[mid] <= s) lo = mid; else hi = mid;
        }
        float4 p = pay[s];
        unsigned dst = gbase[lo] + (s - pfx[lo]);
        sx[dst] = p.x;
        sy[dst] = p.y;
        sz[dst] = p.z;
        unsigned orig = (unsigned)__float_as_int(p.w);
        posbuf[orig] = dst;                    // contiguous 8KB window per block
    }
}

// Lane-contiguous interp: lane x = bins with b&7==x, pinned to XCD via bid&7.
// 192 slots sweep the lane in 512-pt chunks -> front ~3 bins (~3.2MB) per L2.
__global__ __launch_bounds__(256) void interp_lane_kernel(
    const float* __restrict__ sx, const float* __restrict__ sy,
    const float* __restrict__ sz, const float* __restrict__ grid,
    const unsigned* __restrict__ lane_off, float* __restrict__ osort)
{
    int xcd  = blockIdx.x & 7;
    int slot = blockIdx.x >> 3;
    int t = threadIdx.x;
    unsigned start = lane_off[xcd];
    unsigned end   = lane_off[xcd + 1];

    for (unsigned base = start + (unsigned)slot * ICH; base < end;
         base += (unsigned)ISLOTS * ICH) {
        float ax[IPPT], ay[IPPT], az[IPPT];
        int ok[IPPT];
        #pragma unroll
        for (int k = 0; k < IPPT; ++k) {
            unsigned j = base + k * 256 + t;
            ok[k] = (j < end);
            if (ok[k]) { ax[k] = sx[j]; ay[k] = sy[j]; az[k] = sz[j]; }
        }
        #pragma unroll
        for (int k = 0; k < IPPT; ++k) {
            unsigned j = base + k * 256 + t;
            if (ok[k]) {
                bool valid;
                float v = interp_one(ax[k], ay[k], az[k], grid, valid);
                osort[j] = valid ? v : 0.0f;
            }
        }
    }
}

__global__ __launch_bounds__(256) void permute_kernel(
    const float* __restrict__ out_sorted, const unsigned* __restrict__ pos,
    float* __restrict__ out, int n)
{
    int i = blockIdx.x * blockDim.x + threadIdx.x;
    if (i < n) out[i] = out_sorted[pos[i]];
}

extern "C" void kernel_launch(void* const* d_in, const int* in_sizes, int n_in,
                              void* d_out, int out_size, void* d_ws, size_t ws_size,
                              hipStream_t stream) {
    const float* x     = (const float*)d_in[0];
    const float* grid  = (const float*)d_in[1];
    const float* lower = (const float*)d_in[2];
    const float* res   = (const float*)d_in[3];
    float* out = (float*)d_out;

    int n = in_sizes[0] / 3;
    int blocks_pt = (n + 255) / 256;

    // workspace layout
    size_t off_hist   = 0;                               // 64 u32
    size_t off_cursor = 256;                             // 64 u32
    size_t off_lane   = 512;                             // 9 u32
    size_t off_sx     = 768;
    size_t plane      = (((size_t)n * 4) + 255) & ~(size_t)255;
    size_t off_sy     = off_sx + plane;
    size_t off_sz     = off_sy + plane;
    size_t off_pos    = off_sz + plane;
    size_t off_osort  = off_pos + plane;
    size_t needed     = off_osort + plane;               // ~40 MB

    if (ws_size < needed) {
        simplegrid_direct<<<blocks_pt, 256, 0, stream>>>(x, grid, lower, res, out, n);
        return;
    }

    char* ws = (char*)d_ws;
    unsigned* hist   = (unsigned*)(ws + off_hist);
    unsigned* cursor = (unsigned*)(ws + off_cursor);
    unsigned* lane   = (unsigned*)(ws + off_lane);
    float*    sx     = (float*)(ws + off_sx);
    float*    sy     = (float*)(ws + off_sy);
    float*    sz     = (float*)(ws + off_sz);
    unsigned* posbuf = (unsigned*)(ws + off_pos);
    float*    osort  = (float*)(ws + off_osort);

    int blocks_sort = (n + PTS_PER_BLK - 1) / PTS_PER_BLK;

    zero_hist_kernel<<<1, 64, 0, stream>>>(hist);
    hist_kernel<<<blocks_sort, 256, 0, stream>>>(x, lower, res, hist, n);
    scan64_kernel<<<1, 64, 0, stream>>>(hist, cursor, lane);
    scatter_kernel<<<blocks_sort, 256, 0, stream>>>(
        x, lower, res, cursor, sx, sy, sz, posbuf, n);
    interp_lane_kernel<<<8 * ISLOTS, 256, 0, stream>>>(
        sx, sy, sz, grid, lane, osort);
    permute_kernel<<<blocks_pt, 256, 0, stream>>>(osort, posbuf, out, n);
}

// Round 5
// 155.074 us; speedup vs baseline: 2.3079x; 1.0112x over previous
//
#include <hip/hip_runtime.h>

// Trilinear interpolation over a 256^3 f32 grid. Round 5:
//  - 64 coarse spatial bins, block-aggregated counting sort (rounds 3-4)
//  - lane-contiguous sorted layout, XCD-pinned interp sweep (round 4)
//  - NEW: interp is explicitly phase-split (offsets -> 16 batched gathers ->
//    weights+combine) so each wave keeps 16 loads in flight; addresses are
//    clamped so invalid points can't read OOB, output zero-selected instead.

#define CELL_SHIFT 6          // 64 cells per bin axis
#define NBINS 64
#define PTS_PER_BLK 2048
#define PPT 8                 // points per thread in hist/scatter (block=256)

#define ISLOTS 192            // interp slots per lane
#define IPPT 2                // interp points per thread
#define ICH (IPPT * 256)      // interp chunk size (points)

__device__ __forceinline__ float interp_one(float ix, float iy, float iz,
                                            const float* __restrict__ g,
                                            bool& valid) {
    valid = (ix >= 0.0f) && (ix <= 255.0f) &&
            (iy >= 0.0f) && (iy <= 255.0f) &&
            (iz >= 0.0f) && (iz <= 255.0f);
    if (!valid) return 0.0f;

    float flx = floorf(ix), fcx = ceilf(ix);
    float fly = floorf(iy), fcy = ceilf(iy);
    float flz = floorf(iz), fcz = ceilf(iz);

    int x0 = (int)flx, x1 = (int)fcx;
    int y0 = (int)fly, y1 = (int)fcy;
    int z0 = (int)flz, z1 = (int)fcz;

    float wsx = ix - flx; if (wsx == 0.0f) wsx = 1.0f;
    float wux = fcx - ix; if (wux == 0.0f) wux = 1.0f;
    float wsy = iy - fly; if (wsy == 0.0f) wsy = 1.0f;
    float wuy = fcy - iy; if (wuy == 0.0f) wuy = 1.0f;
    float wsz = iz - flz; if (wsz == 0.0f) wsz = 1.0f;
    float wuz = fcz - iz; if (wuz == 0.0f) wuz = 1.0f;

    int bx0 = x0 << 16, bx1 = x1 << 16;
    int by0 = y0 << 8,  by1 = y1 << 8;

    float v0 = g[bx0 + by0 + z0];  float w0 = wux * wuy * wuz;
    float v1 = g[bx1 + by0 + z0];  float w1 = wsx * wuy * wuz;
    float v2 = g[bx0 + by1 + z0];  float w2 = wux * wsy * wuz;
    float v3 = g[bx1 + by1 + z0];  float w3 = wsx * wsy * wuz;
    float v4 = g[bx0 + by0 + z1];  float w4 = wux * wuy * wsz;
    float v5 = g[bx1 + by0 + z1];  float w5 = wsx * wuy * wsz;
    float v6 = g[bx0 + by1 + z1];  float w6 = wux * wsy * wsz;
    float v7 = g[bx1 + by1 + z1];  float w7 = wsx * wsy * wsz;

    float num = v0 * w0 + v1 * w1 + v2 * w2 + v3 * w3 +
                v4 * w4 + v5 * w5 + v6 * w6 + v7 * w7;
    float den = w0 + w1 + w2 + w3 + w4 + w5 + w6 + w7;
    return num / den;
}

__device__ __forceinline__ unsigned bin_key(float ix, float iy, float iz) {
    ix = fminf(fmaxf(ix, 0.0f), 255.0f);
    iy = fminf(fmaxf(iy, 0.0f), 255.0f);
    iz = fminf(fmaxf(iz, 0.0f), 255.0f);
    int bx = ((int)ix) >> CELL_SHIFT;
    int by = ((int)iy) >> CELL_SHIFT;
    int bz = ((int)iz) >> CELL_SHIFT;
    return (unsigned)((bx << 4) | (by << 2) | bz);   // 64 bins
}

// ---------- fallback (round-1) kernel ----------
__global__ __launch_bounds__(256) void simplegrid_direct(
    const float* __restrict__ x, const float* __restrict__ grid,
    const float* __restrict__ lower, const float* __restrict__ res,
    float* __restrict__ out, int n)
{
    int i = blockIdx.x * blockDim.x + threadIdx.x;
    if (i >= n) return;
    float ix = (x[3 * i + 0] - lower[0]) / res[0];
    float iy = (x[3 * i + 1] - lower[1]) / res[1];
    float iz = (x[3 * i + 2] - lower[2]) / res[2];
    bool valid;
    float v = interp_one(ix, iy, iz, grid, valid);
    out[i] = valid ? v : 0.0f;
}

// ---------- sorted pipeline ----------
__global__ __launch_bounds__(64) void zero_hist_kernel(unsigned* hist) {
    hist[threadIdx.x] = 0u;
}

__global__ __launch_bounds__(256) void hist_kernel(
    const float* __restrict__ x, const float* __restrict__ lower,
    const float* __restrict__ res, unsigned* __restrict__ hist, int n)
{
    __shared__ unsigned lcnt[NBINS];
    int t = threadIdx.x;
    if (t < NBINS) lcnt[t] = 0u;
    __syncthreads();

    float l0 = lower[0], l1 = lower[1], l2 = lower[2];
    float r0 = res[0],   r1 = res[1],   r2 = res[2];
    int base = blockIdx.x * PTS_PER_BLK;
    #pragma unroll
    for (int k = 0; k < PPT; ++k) {
        int p = base + k * 256 + t;
        if (p < n) {
            float ix = (x[3 * p + 0] - l0) / r0;
            float iy = (x[3 * p + 1] - l1) / r1;
            float iz = (x[3 * p + 2] - l2) / r2;
            atomicAdd(&lcnt[bin_key(ix, iy, iz)], 1u);
        }
    }
    __syncthreads();
    if (t < NBINS && lcnt[t]) atomicAdd(&hist[t], lcnt[t]);
}

// Scan in permuted rank order rank(b) = ((b&7)<<3)|(b>>3) (involution), so
// bins with b&7==x (lane x, pinned to XCD x) occupy a contiguous range.
__global__ __launch_bounds__(64) void scan64_kernel(
    const unsigned* __restrict__ hist, unsigned* __restrict__ cursor,
    unsigned* __restrict__ lane_off)
{
    int t = threadIdx.x;                       // t = rank
    int b = ((t & 7) << 3) | (t >> 3);         // bin at this rank
    unsigned v = hist[b];
    unsigned s = v;
    #pragma unroll
    for (int off = 1; off < 64; off <<= 1) {
        unsigned u = __shfl_up(s, off);
        if (t >= off) s += u;
    }
    cursor[b] = s - v;                         // exclusive prefix (permuted order)
    if ((t & 7) == 0) lane_off[t >> 3] = s - v;
    if (t == 63)      lane_off[8] = s;
}

__global__ __launch_bounds__(256) void scatter_kernel(
    const float* __restrict__ x, const float* __restrict__ lower,
    const float* __restrict__ res, unsigned* __restrict__ cursor,
    float* __restrict__ sx, float* __restrict__ sy, float* __restrict__ sz,
    unsigned* __restrict__ posbuf, int n)
{
    __shared__ float4  pay[PTS_PER_BLK];        // 32 KB
    __shared__ unsigned cnt[NBINS];
    __shared__ unsigned pfx[NBINS + 1];
    __shared__ unsigned lcur[NBINS];
    __shared__ unsigned gbase[NBINS];

    int t = threadIdx.x;
    if (t < NBINS) cnt[t] = 0u;
    __syncthreads();

    float l0 = lower[0], l1 = lower[1], l2 = lower[2];
    float r0 = res[0],   r1 = res[1],   r2 = res[2];
    int base = blockIdx.x * PTS_PER_BLK;

    float px[PPT], py[PPT], pz[PPT];
    unsigned key[PPT];
    #pragma unroll
    for (int k = 0; k < PPT; ++k) {
        int p = base + k * 256 + t;
        if (p < n) {
            px[k] = (x[3 * p + 0] - l0) / r0;
            py[k] = (x[3 * p + 1] - l1) / r1;
            pz[k] = (x[3 * p + 2] - l2) / r2;
            key[k] = bin_key(px[k], py[k], pz[k]);
            atomicAdd(&cnt[key[k]], 1u);
        }
    }
    __syncthreads();

    if (t < NBINS) {
        unsigned v = cnt[t];
        unsigned s = v;
        #pragma unroll
        for (int off = 1; off < 64; off <<= 1) {
            unsigned u = __shfl_up(s, off);
            if (t >= off) s += u;
        }
        pfx[t] = s - v;
        lcur[t] = s - v;
        if (t == NBINS - 1) pfx[NBINS] = s;
    }
    __syncthreads();

    #pragma unroll
    for (int k = 0; k < PPT; ++k) {
        int p = base + k * 256 + t;
        if (p < n) {
            unsigned lp = atomicAdd(&lcur[key[k]], 1u);
            pay[lp] = make_float4(px[k], py[k], pz[k], __int_as_float(p));
        }
    }
    if (t < NBINS && cnt[t]) gbase[t] = atomicAdd(&cursor[t], cnt[t]);
    __syncthreads();

    unsigned total = pfx[NBINS];
    for (unsigned s = t; s < total; s += 256) {
        unsigned lo = 0, hi = NBINS;
        #pragma unroll
        for (int it = 0; it < 6; ++it) {
            unsigned mid = (lo + hi) >> 1;
            if (pfx[mid] <= s) lo = mid; else hi = mid;
        }
        float4 p = pay[s];
        unsigned dst = gbase[lo] + (s - pfx[lo]);
        sx[dst] = p.x;
        sy[dst] = p.y;
        sz[dst] = p.z;
        unsigned orig = (unsigned)__float_as_int(p.w);
        posbuf[orig] = dst;
    }
}

// Batched lane interp: per iteration each thread computes 16 clamped offsets,
// issues all 16 gathers, then does weight math (overlaps in-flight loads).
__global__ __launch_bounds__(256) void interp_lane_kernel(
    const float* __restrict__ sx, const float* __restrict__ sy,
    const float* __restrict__ sz, const float* __restrict__ grid,
    const unsigned* __restrict__ lane_off, float* __restrict__ osort)
{
    int xcd  = blockIdx.x & 7;
    int slot = blockIdx.x >> 3;
    int t = threadIdx.x;
    unsigned start = lane_off[xcd];
    unsigned end   = lane_off[xcd + 1];

    for (unsigned base = start + (unsigned)slot * ICH; base < end;
         base += (unsigned)ISLOTS * ICH) {
        float ax[IPPT], ay[IPPT], az[IPPT];
        int ok[IPPT];
        #pragma unroll
        for (int k = 0; k < IPPT; ++k) {
            unsigned j = base + k * 256 + t;
            ok[k] = (j < end);
            unsigned js = ok[k] ? j : (end - 1);   // clamp (end>start in loop)
            ax[k] = sx[js]; ay[k] = sy[js]; az[k] = sz[js];
        }

        // phase 1: clamped integer corner offsets (addresses never OOB)
        int off[IPPT][8];
        #pragma unroll
        for (int k = 0; k < IPPT; ++k) {
            float cx = fminf(fmaxf(ax[k], 0.0f), 255.0f);
            float cy = fminf(fmaxf(ay[k], 0.0f), 255.0f);
            float cz = fminf(fmaxf(az[k], 0.0f), 255.0f);
            int bx0 = ((int)floorf(cx)) << 16, bx1 = ((int)ceilf(cx)) << 16;
            int by0 = ((int)floorf(cy)) << 8,  by1 = ((int)ceilf(cy)) << 8;
            int z0  = (int)floorf(cz),         z1  = (int)ceilf(cz);
            off[k][0] = bx0 + by0 + z0;
            off[k][1] = bx1 + by0 + z0;
            off[k][2] = bx0 + by1 + z0;
            off[k][3] = bx1 + by1 + z0;
            off[k][4] = bx0 + by0 + z1;
            off[k][5] = bx1 + by0 + z1;
            off[k][6] = bx0 + by1 + z1;
            off[k][7] = bx1 + by1 + z1;
        }

        // phase 2: issue all gathers
        float v[IPPT][8];
        #pragma unroll
        for (int k = 0; k < IPPT; ++k) {
            #pragma unroll
            for (int c = 0; c < 8; ++c) v[k][c] = grid[off[k][c]];
        }

        // phase 3: weights + combine (VALU overlaps loads in flight)
        #pragma unroll
        for (int k = 0; k < IPPT; ++k) {
            float ix = ax[k], iy = ay[k], iz = az[k];
            bool valid = (ix >= 0.0f) && (ix <= 255.0f) &&
                         (iy >= 0.0f) && (iy <= 255.0f) &&
                         (iz >= 0.0f) && (iz <= 255.0f);
            float flx = floorf(ix), fcx = ceilf(ix);
            float fly = floorf(iy), fcy = ceilf(iy);
            float flz = floorf(iz), fcz = ceilf(iz);
            float wsx = ix - flx; if (wsx == 0.0f) wsx = 1.0f;
            float wux = fcx - ix; if (wux == 0.0f) wux = 1.0f;
            float wsy = iy - fly; if (wsy == 0.0f) wsy = 1.0f;
            float wuy = fcy - iy; if (wuy == 0.0f) wuy = 1.0f;
            float wsz = iz - flz; if (wsz == 0.0f) wsz = 1.0f;
            float wuz = fcz - iz; if (wuz == 0.0f) wuz = 1.0f;

            float w0 = wux * wuy * wuz, w1 = wsx * wuy * wuz;
            float w2 = wux * wsy * wuz, w3 = wsx * wsy * wuz;
            float w4 = wux * wuy * wsz, w5 = wsx * wuy * wsz;
            float w6 = wux * wsy * wsz, w7 = wsx * wsy * wsz;

            float num = v[k][0] * w0 + v[k][1] * w1 + v[k][2] * w2 + v[k][3] * w3 +
                        v[k][4] * w4 + v[k][5] * w5 + v[k][6] * w6 + v[k][7] * w7;
            float den = w0 + w1 + w2 + w3 + w4 + w5 + w6 + w7;
            float r = valid ? (num / den) : 0.0f;
            if (ok[k]) osort[base + k * 256 + t] = r;
        }
    }
}

__global__ __launch_bounds__(256) void permute_kernel(
    const float* __restrict__ out_sorted, const unsigned* __restrict__ pos,
    float* __restrict__ out, int n)
{
    int i = blockIdx.x * blockDim.x + threadIdx.x;
    if (i < n) out[i] = out_sorted[pos[i]];
}

extern "C" void kernel_launch(void* const* d_in, const int* in_sizes, int n_in,
                              void* d_out, int out_size, void* d_ws, size_t ws_size,
                              hipStream_t stream) {
    const float* x     = (const float*)d_in[0];
    const float* grid  = (const float*)d_in[1];
    const float* lower = (const float*)d_in[2];
    const float* res   = (const float*)d_in[3];
    float* out = (float*)d_out;

    int n = in_sizes[0] / 3;
    int blocks_pt = (n + 255) / 256;

    // workspace layout
    size_t off_hist   = 0;                               // 64 u32
    size_t off_cursor = 256;                             // 64 u32
    size_t off_lane   = 512;                             // 9 u32
    size_t off_sx     = 768;
    size_t plane      = (((size_t)n * 4) + 255) & ~(size_t)255;
    size_t off_sy     = off_sx + plane;
    size_t off_sz     = off_sy + plane;
    size_t off_pos    = off_sz + plane;
    size_t off_osort  = off_pos + plane;
    size_t needed     = off_osort + plane;               // ~40 MB

    if (ws_size < needed) {
        simplegrid_direct<<<blocks_pt, 256, 0, stream>>>(x, grid, lower, res, out, n);
        return;
    }

    char* ws = (char*)d_ws;
    unsigned* hist   = (unsigned*)(ws + off_hist);
    unsigned* cursor = (unsigned*)(ws + off_cursor);
    unsigned* lane   = (unsigned*)(ws + off_lane);
    float*    sx     = (float*)(ws + off_sx);
    float*    sy     = (float*)(ws + off_sy);
    float*    sz     = (float*)(ws + off_sz);
    unsigned* posbuf = (unsigned*)(ws + off_pos);
    float*    osort  = (float*)(ws + off_osort);

    int blocks_sort = (n + PTS_PER_BLK - 1) / PTS_PER_BLK;

    zero_hist_kernel<<<1, 64, 0, stream>>>(hist);
    hist_kernel<<<blocks_sort, 256, 0, stream>>>(x, lower, res, hist, n);
    scan64_kernel<<<1, 64, 0, stream>>>(hist, cursor, lane);
    scatter_kernel<<<blocks_sort, 256, 0, stream>>>(
        x, lower, res, cursor, sx, sy, sz, posbuf, n);
    interp_lane_kernel<<<8 * ISLOTS, 256, 0, stream>>>(
        sx, sy, sz, grid, lane, osort);
    permute_kernel<<<blocks_pt, 256, 0, stream>>>(osort, posbuf, out, n);
}

// Round 6
// 125.445 us; speedup vs baseline: 2.8531x; 1.2362x over previous
//
#include <hip/hip_runtime.h>

// Trilinear interpolation over a 256^3 f32 grid. Round 6:
//  - 512 spatial bins of 32^3 cells; exact counting sort (hist -> scan ->
//    block-aggregated scatter with LDS flush, pos[orig]=dst at placement)
//  - interp: ONE BLOCK PER BIN stages the bin's 33^3 halo region (143.7KB)
//    into dynamic LDS, then all gathers come from LDS (bypasses the ~1GB of
//    random 64B L2 transactions that capped rounds 4-5)
//  - streaming out_sorted + final gather-permute

#define CSH 5                 // 32 cells per bin axis
#define NBINS 512             // 8 x 8 x 8
#define SPTS 4096             // points per scatter/hist block
#define SPPT 8                // points per thread (512-thread blocks)

#define RA 33                 // region edge (32 + 1 halo)
#define RAA (RA * RA)         // 1089
#define RN (RA * RA * RA)     // 35937 floats = 143748 B

__device__ __forceinline__ float interp_one(float ix, float iy, float iz,
                                            const float* __restrict__ g,
                                            bool& valid) {
    valid = (ix >= 0.0f) && (ix <= 255.0f) &&
            (iy >= 0.0f) && (iy <= 255.0f) &&
            (iz >= 0.0f) && (iz <= 255.0f);
    if (!valid) return 0.0f;

    float flx = floorf(ix), fcx = ceilf(ix);
    float fly = floorf(iy), fcy = ceilf(iy);
    float flz = floorf(iz), fcz = ceilf(iz);

    int x0 = (int)flx, x1 = (int)fcx;
    int y0 = (int)fly, y1 = (int)fcy;
    int z0 = (int)flz, z1 = (int)fcz;

    float wsx = ix - flx; if (wsx == 0.0f) wsx = 1.0f;
    float wux = fcx - ix; if (wux == 0.0f) wux = 1.0f;
    float wsy = iy - fly; if (wsy == 0.0f) wsy = 1.0f;
    float wuy = fcy - iy; if (wuy == 0.0f) wuy = 1.0f;
    float wsz = iz - flz; if (wsz == 0.0f) wsz = 1.0f;
    float wuz = fcz - iz; if (wuz == 0.0f) wuz = 1.0f;

    int bx0 = x0 << 16, bx1 = x1 << 16;
    int by0 = y0 << 8,  by1 = y1 << 8;

    float v0 = g[bx0 + by0 + z0];  float w0 = wux * wuy * wuz;
    float v1 = g[bx1 + by0 + z0];  float w1 = wsx * wuy * wuz;
    float v2 = g[bx0 + by1 + z0];  float w2 = wux * wsy * wuz;
    float v3 = g[bx1 + by1 + z0];  float w3 = wsx * wsy * wuz;
    float v4 = g[bx0 + by0 + z1];  float w4 = wux * wuy * wsz;
    float v5 = g[bx1 + by0 + z1];  float w5 = wsx * wuy * wsz;
    float v6 = g[bx0 + by1 + z1];  float w6 = wux * wsy * wsz;
    float v7 = g[bx1 + by1 + z1];  float w7 = wsx * wsy * wsz;

    float num = v0 * w0 + v1 * w1 + v2 * w2 + v3 * w3 +
                v4 * w4 + v5 * w5 + v6 * w6 + v7 * w7;
    float den = w0 + w1 + w2 + w3 + w4 + w5 + w6 + w7;
    return num / den;
}

__device__ __forceinline__ unsigned bin_key(float ix, float iy, float iz) {
    ix = fminf(fmaxf(ix, 0.0f), 255.0f);
    iy = fminf(fmaxf(iy, 0.0f), 255.0f);
    iz = fminf(fmaxf(iz, 0.0f), 255.0f);
    int bx = ((int)ix) >> CSH;
    int by = ((int)iy) >> CSH;
    int bz = ((int)iz) >> CSH;
    return (unsigned)((bx << 6) | (by << 3) | bz);   // 512 bins
}

// ---------- fallback (round-1) kernel ----------
__global__ __launch_bounds__(256) void simplegrid_direct(
    const float* __restrict__ x, const float* __restrict__ grid,
    const float* __restrict__ lower, const float* __restrict__ res,
    float* __restrict__ out, int n)
{
    int i = blockIdx.x * blockDim.x + threadIdx.x;
    if (i >= n) return;
    float ix = (x[3 * i + 0] - lower[0]) / res[0];
    float iy = (x[3 * i + 1] - lower[1]) / res[1];
    float iz = (x[3 * i + 2] - lower[2]) / res[2];
    bool valid;
    float v = interp_one(ix, iy, iz, grid, valid);
    out[i] = valid ? v : 0.0f;
}

// ---------- sorted pipeline ----------
__global__ __launch_bounds__(512) void zero_hist_kernel(unsigned* hist) {
    hist[threadIdx.x] = 0u;
}

__global__ __launch_bounds__(512) void hist_kernel(
    const float* __restrict__ x, const float* __restrict__ lower,
    const float* __restrict__ res, unsigned* __restrict__ hist, int n)
{
    __shared__ unsigned lcnt[NBINS];
    int t = threadIdx.x;
    lcnt[t] = 0u;
    __syncthreads();

    float l0 = lower[0], l1 = lower[1], l2 = lower[2];
    float r0 = res[0],   r1 = res[1],   r2 = res[2];
    int base = blockIdx.x * SPTS;
    #pragma unroll
    for (int k = 0; k < SPPT; ++k) {
        int p = base + k * 512 + t;
        if (p < n) {
            float ix = (x[3 * p + 0] - l0) / r0;
            float iy = (x[3 * p + 1] - l1) / r1;
            float iz = (x[3 * p + 2] - l2) / r2;
            atomicAdd(&lcnt[bin_key(ix, iy, iz)], 1u);
        }
    }
    __syncthreads();
    if (lcnt[t]) atomicAdd(&hist[t], lcnt[t]);
}

// 512-bin exclusive scan, one block of 512 threads (8 waves).
// Writes pstart[0..512] (bin boundaries) and seeds cursor.
__global__ __launch_bounds__(512) void scan512_kernel(
    const unsigned* __restrict__ hist, unsigned* __restrict__ cursor,
    unsigned* __restrict__ pstart)
{
    __shared__ unsigned wsum[8];
    int t = threadIdx.x;
    int lane = t & 63, wave = t >> 6;
    unsigned v = hist[t];
    unsigned s = v;
    #pragma unroll
    for (int off = 1; off < 64; off <<= 1) {
        unsigned u = __shfl_up(s, off);
        if (lane >= off) s += u;
    }
    if (lane == 63) wsum[wave] = s;
    __syncthreads();
    unsigned woff = 0;
    for (int w = 0; w < 8; ++w) if (w < wave) woff += wsum[w];
    unsigned excl = woff + s - v;
    pstart[t] = excl;
    cursor[t] = excl;
    if (t == 511) pstart[512] = excl + v;
}

__global__ __launch_bounds__(512) void scatter_kernel(
    const float* __restrict__ x, const float* __restrict__ lower,
    const float* __restrict__ res, unsigned* __restrict__ cursor,
    float* __restrict__ sx, float* __restrict__ sy, float* __restrict__ sz,
    unsigned* __restrict__ posbuf, int n)
{
    __shared__ float sxl[SPTS], syl[SPTS], szl[SPTS];       // 48 KB
    __shared__ unsigned cnt[NBINS], pfx[NBINS], lcur[NBINS], gbase[NBINS];
    __shared__ unsigned wsum[8];

    int t = threadIdx.x;
    int lane = t & 63, wave = t >> 6;
    cnt[t] = 0u;
    __syncthreads();

    float l0 = lower[0], l1 = lower[1], l2 = lower[2];
    float r0 = res[0],   r1 = res[1],   r2 = res[2];
    int base = blockIdx.x * SPTS;

    float px[SPPT], py[SPPT], pz[SPPT];
    unsigned key[SPPT];
    #pragma unroll
    for (int k = 0; k < SPPT; ++k) {
        int p = base + k * 512 + t;
        if (p < n) {
            px[k] = (x[3 * p + 0] - l0) / r0;
            py[k] = (x[3 * p + 1] - l1) / r1;
            pz[k] = (x[3 * p + 2] - l2) / r2;
            key[k] = bin_key(px[k], py[k], pz[k]);
            atomicAdd(&cnt[key[k]], 1u);
        }
    }
    __syncthreads();

    // exclusive prefix over 512 bins (8 waves)
    unsigned v = cnt[t];
    unsigned s = v;
    #pragma unroll
    for (int off = 1; off < 64; off <<= 1) {
        unsigned u = __shfl_up(s, off);
        if (lane >= off) s += u;
    }
    if (lane == 63) wsum[wave] = s;
    __syncthreads();
    unsigned woff = 0, tot = 0;
    for (int w = 0; w < 8; ++w) { if (w < wave) woff += wsum[w]; tot += wsum[w]; }
    unsigned excl = woff + s - v;
    pfx[t] = excl;
    lcur[t] = excl;
    gbase[t] = v ? atomicAdd(&cursor[t], v) : 0u;
    __syncthreads();

    // placement into LDS (bin-sorted) + pos written directly (coalesced addr)
    #pragma unroll
    for (int k = 0; k < SPPT; ++k) {
        int p = base + k * 512 + t;
        if (p < n) {
            unsigned lp = atomicAdd(&lcur[key[k]], 1u);
            sxl[lp] = px[k]; syl[lp] = py[k]; szl[lp] = pz[k];
            posbuf[p] = gbase[key[k]] + (lp - pfx[key[k]]);
        }
    }
    __syncthreads();

    // flush in sorted order -> contiguous per-bin segments
    for (unsigned q = t; q < tot; q += 512) {
        unsigned lo = 0, hi = NBINS;
        #pragma unroll
        for (int it = 0; it < 9; ++it) {
            unsigned mid = (lo + hi) >> 1;
            if (pfx[mid] <= q) lo = mid; else hi = mid;
        }
        unsigned dst = gbase[lo] + (q - pfx[lo]);
        sx[dst] = sxl[q];
        sy[dst] = syl[q];
        sz[dst] = szl[q];
    }
}

// One block per bin: stage 33^3 halo region into LDS, gather from LDS.
__global__ __launch_bounds__(256) void interp_lds_kernel(
    const float* __restrict__ sx, const float* __restrict__ sy,
    const float* __restrict__ sz, const float* __restrict__ grid,
    const unsigned* __restrict__ pstart, float* __restrict__ osort)
{
    extern __shared__ float lds[];
    int b = blockIdx.x;
    int t = threadIdx.x;
    int bx0 = ((b >> 6) & 7) << CSH;
    int by0 = ((b >> 3) & 7) << CSH;
    int bz0 = (b & 7) << CSH;

    // stage region: idx = lx*1089 + ly*33 + lz (z contiguous -> coalesced rows)
    int i = t;
    for (; i + 768 < RN; i += 1024) {
        #pragma unroll
        for (int u = 0; u < 4; ++u) {
            int e = i + u * 256;
            int lx = e / RAA;
            int r  = e - lx * RAA;
            int ly = r / RA;
            int lz = r - ly * RA;
            int gx = bx0 + lx; if (gx > 255) gx = 255;
            int gy = by0 + ly; if (gy > 255) gy = 255;
            int gz = bz0 + lz; if (gz > 255) gz = 255;
            lds[e] = grid[(gx << 16) + (gy << 8) + gz];
        }
    }
    for (; i < RN; i += 256) {
        int lx = i / RAA;
        int r  = i - lx * RAA;
        int ly = r / RA;
        int lz = r - ly * RA;
        int gx = bx0 + lx; if (gx > 255) gx = 255;
        int gy = by0 + ly; if (gy > 255) gy = 255;
        int gz = bz0 + lz; if (gz > 255) gz = 255;
        lds[i] = grid[(gx << 16) + (gy << 8) + gz];
    }
    __syncthreads();

    float fbx = (float)bx0, fby = (float)by0, fbz = (float)bz0;
    unsigned start = pstart[b];
    unsigned end   = pstart[b + 1];

    for (unsigned j = start + t; j < end; j += 256) {
        float ix = sx[j], iy = sy[j], iz = sz[j];
        bool valid = (ix >= 0.0f) && (ix <= 255.0f) &&
                     (iy >= 0.0f) && (iy <= 255.0f) &&
                     (iz >= 0.0f) && (iz <= 255.0f);
        // local (in-region) coords; clamp matches bin_key's clamp
        float fx = fminf(fmaxf(ix, 0.0f), 255.0f) - fbx;
        float fy = fminf(fmaxf(iy, 0.0f), 255.0f) - fby;
        float fz = fminf(fmaxf(iz, 0.0f), 255.0f) - fbz;

        float flx = floorf(fx), fcx = ceilf(fx);
        float fly = floorf(fy), fcy = ceilf(fy);
        float flz = floorf(fz), fcz = ceilf(fz);
        int x0 = (int)flx, x1 = (int)fcx;
        int y0 = (int)fly, y1 = (int)fcy;
        int z0 = (int)flz, z1 = (int)fcz;

        float wsx = fx - flx; if (wsx == 0.0f) wsx = 1.0f;
        float wux = fcx - fx; if (wux == 0.0f) wux = 1.0f;
        float wsy = fy - fly; if (wsy == 0.0f) wsy = 1.0f;
        float wuy = fcy - fy; if (wuy == 0.0f) wuy = 1.0f;
        float wsz = fz - flz; if (wsz == 0.0f) wsz = 1.0f;
        float wuz = fcz - fz; if (wuz == 0.0f) wuz = 1.0f;

        int ax0 = x0 * RAA, ax1 = x1 * RAA;
        int ay0 = y0 * RA,  ay1 = y1 * RA;

        float v0 = lds[ax0 + ay0 + z0];  float w0 = wux * wuy * wuz;
        float v1 = lds[ax1 + ay0 + z0];  float w1 = wsx * wuy * wuz;
        float v2 = lds[ax0 + ay1 + z0];  float w2 = wux * wsy * wuz;
        float v3 = lds[ax1 + ay1 + z0];  float w3 = wsx * wsy * wuz;
        float v4 = lds[ax0 + ay0 + z1];  float w4 = wux * wuy * wsz;
        float v5 = lds[ax1 + ay0 + z1];  float w5 = wsx * wuy * wsz;
        float v6 = lds[ax0 + ay1 + z1];  float w6 = wux * wsy * wsz;
        float v7 = lds[ax1 + ay1 + z1];  float w7 = wsx * wsy * wsz;

        float num = v0 * w0 + v1 * w1 + v2 * w2 + v3 * w3 +
                    v4 * w4 + v5 * w5 + v6 * w6 + v7 * w7;
        float den = w0 + w1 + w2 + w3 + w4 + w5 + w6 + w7;
        osort[j] = valid ? (num / den) : 0.0f;
    }
}

__global__ __launch_bounds__(256) void permute_kernel(
    const float* __restrict__ out_sorted, const unsigned* __restrict__ pos,
    float* __restrict__ out, int n)
{
    int i = blockIdx.x * blockDim.x + threadIdx.x;
    if (i < n) out[i] = out_sorted[pos[i]];
}

extern "C" void kernel_launch(void* const* d_in, const int* in_sizes, int n_in,
                              void* d_out, int out_size, void* d_ws, size_t ws_size,
                              hipStream_t stream) {
    const float* x     = (const float*)d_in[0];
    const float* grid  = (const float*)d_in[1];
    const float* lower = (const float*)d_in[2];
    const float* res   = (const float*)d_in[3];
    float* out = (float*)d_out;

    int n = in_sizes[0] / 3;
    int blocks_pt = (n + 255) / 256;

    // workspace layout
    size_t off_hist   = 0;                                // 512 u32
    size_t off_cursor = 2048;                             // 512 u32
    size_t off_pstart = 4096;                             // 513 u32
    size_t off_sx     = 6400;
    size_t plane      = (((size_t)n * 4) + 255) & ~(size_t)255;
    size_t off_sy     = off_sx + plane;
    size_t off_sz     = off_sy + plane;
    size_t off_pos    = off_sz + plane;
    size_t off_osort  = off_pos + plane;
    size_t needed     = off_osort + plane;                // ~40 MB

    bool lds_ok = (hipFuncSetAttribute(
        (const void*)interp_lds_kernel,
        hipFuncAttributeMaxDynamicSharedMemorySize,
        RN * (int)sizeof(float)) == hipSuccess);

    if (ws_size < needed || !lds_ok) {
        simplegrid_direct<<<blocks_pt, 256, 0, stream>>>(x, grid, lower, res, out, n);
        return;
    }

    char* ws = (char*)d_ws;
    unsigned* hist   = (unsigned*)(ws + off_hist);
    unsigned* cursor = (unsigned*)(ws + off_cursor);
    unsigned* pstart = (unsigned*)(ws + off_pstart);
    float*    sx     = (float*)(ws + off_sx);
    float*    sy     = (float*)(ws + off_sy);
    float*    sz     = (float*)(ws + off_sz);
    unsigned* posbuf = (unsigned*)(ws + off_pos);
    float*    osort  = (float*)(ws + off_osort);

    int blocks_sort = (n + SPTS - 1) / SPTS;

    zero_hist_kernel<<<1, 512, 0, stream>>>(hist);
    hist_kernel<<<blocks_sort, 512, 0, stream>>>(x, lower, res, hist, n);
    scan512_kernel<<<1, 512, 0, stream>>>(hist, cursor, pstart);
    scatter_kernel<<<blocks_sort, 512, 0, stream>>>(
        x, lower, res, cursor, sx, sy, sz, posbuf, n);
    interp_lds_kernel<<<NBINS, 256, RN * sizeof(float), stream>>>(
        sx, sy, sz, grid, pstart, osort);
    permute_kernel<<<blocks_pt, 256, 0, stream>>>(osort, posbuf, out, n);
}

// Round 7
// 93.479 us; speedup vs baseline: 3.8287x; 1.3420x over previous
//
#include <hip/hip_runtime.h>

// Trilinear interpolation over a 256^3 f32 grid. Round 7:
//  - 512 spatial bins of 32^3 cells; exact counting sort (round 6)
//  - interp: one block per bin stages the 33^3 halo region (143.7KB) into
//    dynamic LDS, gathers from LDS. NEW: 1024-thread interp blocks ->
//    16 waves/CU (was 4) so staging + stream latency is actually hidden.
//  - streaming out_sorted + final gather-permute

#define CSH 5                 // 32 cells per bin axis
#define NBINS 512             // 8 x 8 x 8
#define SPTS 4096             // points per scatter/hist block
#define SPPT 8                // points per thread (512-thread blocks)

#define RA 33                 // region edge (32 + 1 halo)
#define RAA (RA * RA)         // 1089
#define RN (RA * RA * RA)     // 35937 floats = 143748 B

#define ITHREADS 1024         // interp block size (16 waves)

__device__ __forceinline__ float interp_one(float ix, float iy, float iz,
                                            const float* __restrict__ g,
                                            bool& valid) {
    valid = (ix >= 0.0f) && (ix <= 255.0f) &&
            (iy >= 0.0f) && (iy <= 255.0f) &&
            (iz >= 0.0f) && (iz <= 255.0f);
    if (!valid) return 0.0f;

    float flx = floorf(ix), fcx = ceilf(ix);
    float fly = floorf(iy), fcy = ceilf(iy);
    float flz = floorf(iz), fcz = ceilf(iz);

    int x0 = (int)flx, x1 = (int)fcx;
    int y0 = (int)fly, y1 = (int)fcy;
    int z0 = (int)flz, z1 = (int)fcz;

    float wsx = ix - flx; if (wsx == 0.0f) wsx = 1.0f;
    float wux = fcx - ix; if (wux == 0.0f) wux = 1.0f;
    float wsy = iy - fly; if (wsy == 0.0f) wsy = 1.0f;
    float wuy = fcy - iy; if (wuy == 0.0f) wuy = 1.0f;
    float wsz = iz - flz; if (wsz == 0.0f) wsz = 1.0f;
    float wuz = fcz - iz; if (wuz == 0.0f) wuz = 1.0f;

    int bx0 = x0 << 16, bx1 = x1 << 16;
    int by0 = y0 << 8,  by1 = y1 << 8;

    float v0 = g[bx0 + by0 + z0];  float w0 = wux * wuy * wuz;
    float v1 = g[bx1 + by0 + z0];  float w1 = wsx * wuy * wuz;
    float v2 = g[bx0 + by1 + z0];  float w2 = wux * wsy * wuz;
    float v3 = g[bx1 + by1 + z0];  float w3 = wsx * wsy * wuz;
    float v4 = g[bx0 + by0 + z1];  float w4 = wux * wuy * wsz;
    float v5 = g[bx1 + by0 + z1];  float w5 = wsx * wuy * wsz;
    float v6 = g[bx0 + by1 + z1];  float w6 = wux * wsy * wsz;
    float v7 = g[bx1 + by1 + z1];  float w7 = wsx * wsy * wsz;

    float num = v0 * w0 + v1 * w1 + v2 * w2 + v3 * w3 +
                v4 * w4 + v5 * w5 + v6 * w6 + v7 * w7;
    float den = w0 + w1 + w2 + w3 + w4 + w5 + w6 + w7;
    return num / den;
}

__device__ __forceinline__ unsigned bin_key(float ix, float iy, float iz) {
    ix = fminf(fmaxf(ix, 0.0f), 255.0f);
    iy = fminf(fmaxf(iy, 0.0f), 255.0f);
    iz = fminf(fmaxf(iz, 0.0f), 255.0f);
    int bx = ((int)ix) >> CSH;
    int by = ((int)iy) >> CSH;
    int bz = ((int)iz) >> CSH;
    return (unsigned)((bx << 6) | (by << 3) | bz);   // 512 bins
}

// ---------- fallback (round-1) kernel ----------
__global__ __launch_bounds__(256) void simplegrid_direct(
    const float* __restrict__ x, const float* __restrict__ grid,
    const float* __restrict__ lower, const float* __restrict__ res,
    float* __restrict__ out, int n)
{
    int i = blockIdx.x * blockDim.x + threadIdx.x;
    if (i >= n) return;
    float ix = (x[3 * i + 0] - lower[0]) / res[0];
    float iy = (x[3 * i + 1] - lower[1]) / res[1];
    float iz = (x[3 * i + 2] - lower[2]) / res[2];
    bool valid;
    float v = interp_one(ix, iy, iz, grid, valid);
    out[i] = valid ? v : 0.0f;
}

// ---------- sorted pipeline ----------
__global__ __launch_bounds__(512) void zero_hist_kernel(unsigned* hist) {
    hist[threadIdx.x] = 0u;
}

__global__ __launch_bounds__(512) void hist_kernel(
    const float* __restrict__ x, const float* __restrict__ lower,
    const float* __restrict__ res, unsigned* __restrict__ hist, int n)
{
    __shared__ unsigned lcnt[NBINS];
    int t = threadIdx.x;
    lcnt[t] = 0u;
    __syncthreads();

    float l0 = lower[0], l1 = lower[1], l2 = lower[2];
    float r0 = res[0],   r1 = res[1],   r2 = res[2];
    int base = blockIdx.x * SPTS;
    #pragma unroll
    for (int k = 0; k < SPPT; ++k) {
        int p = base + k * 512 + t;
        if (p < n) {
            float ix = (x[3 * p + 0] - l0) / r0;
            float iy = (x[3 * p + 1] - l1) / r1;
            float iz = (x[3 * p + 2] - l2) / r2;
            atomicAdd(&lcnt[bin_key(ix, iy, iz)], 1u);
        }
    }
    __syncthreads();
    if (lcnt[t]) atomicAdd(&hist[t], lcnt[t]);
}

// 512-bin exclusive scan, one block of 512 threads (8 waves).
__global__ __launch_bounds__(512) void scan512_kernel(
    const unsigned* __restrict__ hist, unsigned* __restrict__ cursor,
    unsigned* __restrict__ pstart)
{
    __shared__ unsigned wsum[8];
    int t = threadIdx.x;
    int lane = t & 63, wave = t >> 6;
    unsigned v = hist[t];
    unsigned s = v;
    #pragma unroll
    for (int off = 1; off < 64; off <<= 1) {
        unsigned u = __shfl_up(s, off);
        if (lane >= off) s += u;
    }
    if (lane == 63) wsum[wave] = s;
    __syncthreads();
    unsigned woff = 0;
    for (int w = 0; w < 8; ++w) if (w < wave) woff += wsum[w];
    unsigned excl = woff + s - v;
    pstart[t] = excl;
    cursor[t] = excl;
    if (t == 511) pstart[512] = excl + v;
}

__global__ __launch_bounds__(512) void scatter_kernel(
    const float* __restrict__ x, const float* __restrict__ lower,
    const float* __restrict__ res, unsigned* __restrict__ cursor,
    float* __restrict__ sx, float* __restrict__ sy, float* __restrict__ sz,
    unsigned* __restrict__ posbuf, int n)
{
    __shared__ float sxl[SPTS], syl[SPTS], szl[SPTS];       // 48 KB
    __shared__ unsigned cnt[NBINS], pfx[NBINS], lcur[NBINS], gbase[NBINS];
    __shared__ unsigned wsum[8];

    int t = threadIdx.x;
    int lane = t & 63, wave = t >> 6;
    cnt[t] = 0u;
    __syncthreads();

    float l0 = lower[0], l1 = lower[1], l2 = lower[2];
    float r0 = res[0],   r1 = res[1],   r2 = res[2];
    int base = blockIdx.x * SPTS;

    float px[SPPT], py[SPPT], pz[SPPT];
    unsigned key[SPPT];
    #pragma unroll
    for (int k = 0; k < SPPT; ++k) {
        int p = base + k * 512 + t;
        if (p < n) {
            px[k] = (x[3 * p + 0] - l0) / r0;
            py[k] = (x[3 * p + 1] - l1) / r1;
            pz[k] = (x[3 * p + 2] - l2) / r2;
            key[k] = bin_key(px[k], py[k], pz[k]);
            atomicAdd(&cnt[key[k]], 1u);
        }
    }
    __syncthreads();

    unsigned v = cnt[t];
    unsigned s = v;
    #pragma unroll
    for (int off = 1; off < 64; off <<= 1) {
        unsigned u = __shfl_up(s, off);
        if (lane >= off) s += u;
    }
    if (lane == 63) wsum[wave] = s;
    __syncthreads();
    unsigned woff = 0, tot = 0;
    for (int w = 0; w < 8; ++w) { if (w < wave) woff += wsum[w]; tot += wsum[w]; }
    unsigned excl = woff + s - v;
    pfx[t] = excl;
    lcur[t] = excl;
    gbase[t] = v ? atomicAdd(&cursor[t], v) : 0u;
    __syncthreads();

    #pragma unroll
    for (int k = 0; k < SPPT; ++k) {
        int p = base + k * 512 + t;
        if (p < n) {
            unsigned lp = atomicAdd(&lcur[key[k]], 1u);
            sxl[lp] = px[k]; syl[lp] = py[k]; szl[lp] = pz[k];
            posbuf[p] = gbase[key[k]] + (lp - pfx[key[k]]);
        }
    }
    __syncthreads();

    for (unsigned q = t; q < tot; q += 512) {
        unsigned lo = 0, hi = NBINS;
        #pragma unroll
        for (int it = 0; it < 9; ++it) {
            unsigned mid = (lo + hi) >> 1;
            if (pfx[mid] <= q) lo = mid; else hi = mid;
        }
        unsigned dst = gbase[lo] + (q - pfx[lo]);
        sx[dst] = sxl[q];
        sy[dst] = syl[q];
        sz[dst] = szl[q];
    }
}

// One block per bin: stage 33^3 halo region into LDS, gather from LDS.
// 1024 threads = 16 waves/CU.
__global__ __launch_bounds__(ITHREADS) void interp_lds_kernel(
    const float* __restrict__ sx, const float* __restrict__ sy,
    const float* __restrict__ sz, const float* __restrict__ grid,
    const unsigned* __restrict__ pstart, float* __restrict__ osort)
{
    extern __shared__ float lds[];
    int b = blockIdx.x;
    int t = threadIdx.x;
    int bx0 = ((b >> 6) & 7) << CSH;
    int by0 = ((b >> 3) & 7) << CSH;
    int bz0 = (b & 7) << CSH;

    // stage region: idx = lx*1089 + ly*33 + lz (z contiguous -> coalesced rows)
    for (int i = t; i < RN; i += ITHREADS) {
        int lx = i / RAA;
        int r  = i - lx * RAA;
        int ly = r / RA;
        int lz = r - ly * RA;
        int gx = bx0 + lx; if (gx > 255) gx = 255;
        int gy = by0 + ly; if (gy > 255) gy = 255;
        int gz = bz0 + lz; if (gz > 255) gz = 255;
        lds[i] = grid[(gx << 16) + (gy << 8) + gz];
    }
    __syncthreads();

    float fbx = (float)bx0, fby = (float)by0, fbz = (float)bz0;
    unsigned start = pstart[b];
    unsigned end   = pstart[b + 1];

    for (unsigned j = start + t; j < end; j += ITHREADS) {
        float ix = sx[j], iy = sy[j], iz = sz[j];
        bool valid = (ix >= 0.0f) && (ix <= 255.0f) &&
                     (iy >= 0.0f) && (iy <= 255.0f) &&
                     (iz >= 0.0f) && (iz <= 255.0f);
        float fx = fminf(fmaxf(ix, 0.0f), 255.0f) - fbx;
        float fy = fminf(fmaxf(iy, 0.0f), 255.0f) - fby;
        float fz = fminf(fmaxf(iz, 0.0f), 255.0f) - fbz;

        float flx = floorf(fx), fcx = ceilf(fx);
        float fly = floorf(fy), fcy = ceilf(fy);
        float flz = floorf(fz), fcz = ceilf(fz);
        int x0 = (int)flx, x1 = (int)fcx;
        int y0 = (int)fly, y1 = (int)fcy;
        int z0 = (int)flz, z1 = (int)fcz;

        float wsx = fx - flx; if (wsx == 0.0f) wsx = 1.0f;
        float wux = fcx - fx; if (wux == 0.0f) wux = 1.0f;
        float wsy = fy - fly; if (wsy == 0.0f) wsy = 1.0f;
        float wuy = fcy - fy; if (wuy == 0.0f) wuy = 1.0f;
        float wsz = fz - flz; if (wsz == 0.0f) wsz = 1.0f;
        float wuz = fcz - fz; if (wuz == 0.0f) wuz = 1.0f;

        int ax0 = x0 * RAA, ax1 = x1 * RAA;
        int ay0 = y0 * RA,  ay1 = y1 * RA;

        float v0 = lds[ax0 + ay0 + z0];  float w0 = wux * wuy * wuz;
        float v1 = lds[ax1 + ay0 + z0];  float w1 = wsx * wuy * wuz;
        float v2 = lds[ax0 + ay1 + z0];  float w2 = wux * wsy * wuz;
        float v3 = lds[ax1 + ay1 + z0];  float w3 = wsx * wsy * wuz;
        float v4 = lds[ax0 + ay0 + z1];  float w4 = wux * wuy * wsz;
        float v5 = lds[ax1 + ay0 + z1];  float w5 = wsx * wuy * wsz;
        float v6 = lds[ax0 + ay1 + z1];  float w6 = wux * wsy * wsz;
        float v7 = lds[ax1 + ay1 + z1];  float w7 = wsx * wsy * wsz;

        float num = v0 * w0 + v1 * w1 + v2 * w2 + v3 * w3 +
                    v4 * w4 + v5 * w5 + v6 * w6 + v7 * w7;
        float den = w0 + w1 + w2 + w3 + w4 + w5 + w6 + w7;
        osort[j] = valid ? (num / den) : 0.0f;
    }
}

__global__ __launch_bounds__(256) void permute_kernel(
    const float* __restrict__ out_sorted, const unsigned* __restrict__ pos,
    float* __restrict__ out, int n)
{
    int i = blockIdx.x * blockDim.x + threadIdx.x;
    if (i < n) out[i] = out_sorted[pos[i]];
}

extern "C" void kernel_launch(void* const* d_in, const int* in_sizes, int n_in,
                              void* d_out, int out_size, void* d_ws, size_t ws_size,
                              hipStream_t stream) {
    const float* x     = (const float*)d_in[0];
    const float* grid  = (const float*)d_in[1];
    const float* lower = (const float*)d_in[2];
    const float* res   = (const float*)d_in[3];
    float* out = (float*)d_out;

    int n = in_sizes[0] / 3;
    int blocks_pt = (n + 255) / 256;

    // workspace layout
    size_t off_hist   = 0;                                // 512 u32
    size_t off_cursor = 2048;                             // 512 u32
    size_t off_pstart = 4096;                             // 513 u32
    size_t off_sx     = 6400;
    size_t plane      = (((size_t)n * 4) + 255) & ~(size_t)255;
    size_t off_sy     = off_sx + plane;
    size_t off_sz     = off_sy + plane;
    size_t off_pos    = off_sz + plane;
    size_t off_osort  = off_pos + plane;
    size_t needed     = off_osort + plane;                // ~40 MB

    bool lds_ok = (hipFuncSetAttribute(
        (const void*)interp_lds_kernel,
        hipFuncAttributeMaxDynamicSharedMemorySize,
        RN * (int)sizeof(float)) == hipSuccess);

    if (ws_size < needed || !lds_ok) {
        simplegrid_direct<<<blocks_pt, 256, 0, stream>>>(x, grid, lower, res, out, n);
        return;
    }

    char* ws = (char*)d_ws;
    unsigned* hist   = (unsigned*)(ws + off_hist);
    unsigned* cursor = (unsigned*)(ws + off_cursor);
    unsigned* pstart = (unsigned*)(ws + off_pstart);
    float*    sx     = (float*)(ws + off_sx);
    float*    sy     = (float*)(ws + off_sy);
    float*    sz     = (float*)(ws + off_sz);
    unsigned* posbuf = (unsigned*)(ws + off_pos);
    float*    osort  = (float*)(ws + off_osort);

    int blocks_sort = (n + SPTS - 1) / SPTS;

    zero_hist_kernel<<<1, 512, 0, stream>>>(hist);
    hist_kernel<<<blocks_sort, 512, 0, stream>>>(x, lower, res, hist, n);
    scan512_kernel<<<1, 512, 0, stream>>>(hist, cursor, pstart);
    scatter_kernel<<<blocks_sort, 512, 0, stream>>>(
        x, lower, res, cursor, sx, sy, sz, posbuf, n);
    interp_lds_kernel<<<NBINS, ITHREADS, RN * sizeof(float), stream>>>(
        sx, sy, sz, grid, pstart, osort);
    permute_kernel<<<blocks_pt, 256, 0, stream>>>(osort, posbuf, out, n);
}